// Round 15
// baseline (170.168 us; speedup 1.0000x reference)
//
#include <hip/hip_runtime.h>
#include <math.h>
#include <cstdint>
#include <cstddef>

typedef unsigned short u16;
typedef short bf16x8 __attribute__((ext_vector_type(8)));
typedef float f32x4 __attribute__((ext_vector_type(4)));
typedef u16 u16x8 __attribute__((ext_vector_type(8)));
typedef u16 u16x4 __attribute__((ext_vector_type(4)));

#define T_LEN 4096
#define NH 12
#define HD 64
#define DMODEL 768
#define GK 768                    // K dim for both GEMMs
#define QKV_STRIDE 6291456ul      // elems per q/k/v tensor = 8192*768

__device__ __forceinline__ u16 f2bf(float x) {
  union { float f; unsigned u; } v; v.f = x;
  unsigned r = v.u + 0x7fffu + ((v.u >> 16) & 1u);
  return (u16)(r >> 16);
}

__device__ __forceinline__ void async16(const u16* g, u16* l) {
  __builtin_amdgcn_global_load_lds(
      (const __attribute__((address_space(1))) unsigned int*)g,
      (__attribute__((address_space(3))) unsigned int*)l, 16, 0, 0);
}

// ---------------- fused fp32 -> bf16 conversion (x + 4 weights, one launch) ----------------
__global__ void cvt_all(const float* __restrict__ x,
                        const float* __restrict__ Wq, const float* __restrict__ Wk,
                        const float* __restrict__ Wv, const float* __restrict__ Wo,
                        u16* __restrict__ xb, u16* __restrict__ wqkv, u16* __restrict__ wo_b) {
  int bx = blockIdx.x;
  const float* s; u16* d; int base;
  if (bx < 6144)      { s = x;  d = xb;             base = bx; }
  else if (bx < 6720) { s = Wq; d = wqkv;           base = bx - 6144; }
  else if (bx < 7296) { s = Wk; d = wqkv + 589824;  base = bx - 6720; }
  else if (bx < 7872) { s = Wv; d = wqkv + 1179648; base = bx - 7296; }
  else                { s = Wo; d = wo_b;           base = bx - 7872; }
  int i = (base * 256 + (int)threadIdx.x) * 4;
  float4 v = *(const float4*)(s + i);
  u16x4 o;
  o[0] = f2bf(v.x); o[1] = f2bf(v.y); o[2] = f2bf(v.z); o[3] = f2bf(v.w);
  *(u16x4*)(d + i) = o;
}

// ---------------- GEMM: C = A[M,K] * B[N,K]^T + bias ----------------
// K-loop skeleton (verified r3..r14): per step {vmcnt(wait); s_barrier;
// ds_read(buf s); stage(buf s+DEPTH-1); MFMA}. DEPTH=3 -> counted
// vmcnt(LPB) (1 batch in flight); DEPTH=2 -> vmcnt(0) (drain; batch s+1
// issued mid-step s). Overwrite safety both depths: stage at step s writes
// the buffer whose readers finished ds_reads before barrier_s.
// MEASURED LEDGER: QKV 4w/128^2/3deep = 50.2; QKV 8w/256x128/3deep = 43.1
// (r14: MfmaUtil 24.5, VALUBusy 16.5, Occ 27, 2 blk/CU + 64-block tail);
// attn = 17.1 (r10 probe); outproj = 21.0 (r11 probe); cvt ~10; fixed
// residue ~70us (harness ws fill + graph -- not source-addressable).
// r15: QKV DEPTH 3->2 (LDS 73.7->49.2KB) -> 3 blocks/CU = 24 waves/CU AND
// single-round grid (576 <= 768 slots, tail gone). r2's drain-regression
// counter-argument: r2 had ZERO unsynced coverer blocks (barrier lockstep
// within the only block-pair); here each draining block has TWO unsynced
// neighbors. Q/K C-tile epilogue split into two 128-row passes (34.8KB)
// to keep the smem union at 49.2KB.
// EPI=3 (NW=8 only): merged QKV. EPI=1 (NW=4): fp32 outproj MI=2, 3-deep.
#define BN 128
#define BK 32
#define CPAD 8   // C-tile row pad (u16) to spread LDS banks on readback

template <int EPI, int MI, int NX, int NW>
__global__ __launch_bounds__(NW * 64)
void gemm_bt(const u16* __restrict__ A, const u16* __restrict__ B,
             const float* __restrict__ bias0, const float* __restrict__ bias1,
             const float* __restrict__ bias2, void* __restrict__ outp) {
  constexpr int NT    = NW * 64;
  constexpr int BMt   = (NW == 8) ? 256 : MI * 32;
  constexpr int DEPTH = (NW == 8) ? 2 : 3;
  constexpr int NSTEP = GK / BK;  // 24
  constexpr int PER = NX / 8;     // x-tiles per XCD group
  constexpr int STG = DEPTH * (BMt + BN) * BK * 2;                 // staging bytes
  constexpr int CSZ = (EPI == 3) ? (BMt / 2) * (BN + CPAD) * 2     // bf16 half C-tile
                                 : 64 * 132 * 4;                   // f32 C-tile
  constexpr int SMEM = STG > CSZ ? STG : CSZ;
  __shared__ __align__(16) char smem[SMEM];
  u16* AsB = (u16*)smem;                        // [DEPTH][BMt*BK]
  u16* BsB = (u16*)smem + DEPTH * BMt * BK;     // [DEPTH][BN*BK]

  const int bid  = blockIdx.x;
  const int xcd  = bid & 7;
  const int slot = bid >> 3;
  const int bx   = xcd * PER + (slot % PER);
  const int by   = slot / PER;

  const int tid  = threadIdx.x;
  const int lane = tid & 63;
  const int wave = tid >> 6;
  const int wm = (NW == 8) ? (wave >> 1) : (wave & 1);
  const int wn = (NW == 8) ? (wave & 1)  : (wave >> 1);
  const long am0 = (long)bx * BMt;
  const long bn0 = (long)by * BN;
  const int r16 = lane & 15;
  const int kh  = lane >> 4;
  const int sw8 = (kh ^ ((r16 >> 1) & 3)) * 8;   // swizzled chunk offset for frag reads

  f32x4 acc[MI][4] = {};

  // staging: lane l -> row l>>2 (of a 16-row slab), global chunk
  // (l&3)^((l>>3)&3); LDS dest lane-linear.
  const int srow   = lane >> 2;
  const int schunk = ((lane & 3) ^ ((lane >> 3) & 3)) * 8;
  const u16* Ag = A + (am0 + wave * 16 + srow) * GK + schunk;
  const u16* Bg = B + (bn0 + wave * 16 + srow) * GK + schunk;

  auto stage = [&](int buf, int kt) {
    u16* Ab = AsB + buf * (BMt * BK);
    u16* Bb = BsB + buf * (BN * BK);
    if constexpr (NW == 8) {
      // A: 16 slabs of 16 rows, 2 per wave (stride 128 rows); B: 8 slabs, 1/wave
#pragma unroll
      for (int s2 = 0; s2 < 2; s2++)
        async16(Ag + (size_t)(s2 * 128) * GK + kt, &Ab[(s2 * 128 + wave * 16) * BK]);
      async16(Bg + kt, &Bb[(wave * 16) * BK]);
    } else {
#pragma unroll
      for (int s2 = 0; s2 < MI / 2; s2++)
        async16(Ag + (size_t)(s2 * 64) * GK + kt, &Ab[(s2 * 64 + wave * 16) * BK]);
      async16(Bg + kt, &Bb[(wave * 16) * BK]);
      async16(Bg + (size_t)64 * GK + kt, &Bb[(64 + wave * 16) * BK]);
    }
  };

  stage(0, 0);                              // batch for step 0
  if constexpr (DEPTH == 3) stage(1, BK);   // batch for step 1
  int cur = 0;
  for (int s = 0; s < NSTEP; ++s) {
    if constexpr (DEPTH == 2) {
      // batch s issued at step s-1 (one MFMA phase of flight); drain it.
      asm volatile("s_waitcnt vmcnt(0)" ::: "memory");
    } else {
      // batch s issued at step s-2; only batch s+1 may stay in flight.
      if (s + 1 < NSTEP) {
        if constexpr (MI == 4) asm volatile("s_waitcnt vmcnt(4)" ::: "memory");
        else                   asm volatile("s_waitcnt vmcnt(3)" ::: "memory");
      } else {
        asm volatile("s_waitcnt vmcnt(0)" ::: "memory");
      }
    }
    __builtin_amdgcn_s_barrier();    // all waves' batch-s loads landed
    asm volatile("" ::: "memory");
    const u16* Ac = AsB + cur * (BMt * BK);
    const u16* Bc = BsB + cur * (BN * BK);
    bf16x8 af[MI], bfr[4];
#pragma unroll
    for (int i = 0; i < MI; i++)
      af[i] = *(const bf16x8*)&Ac[(wm * MI * 16 + i * 16 + r16) * BK + sw8];
#pragma unroll
    for (int j = 0; j < 4; j++)
      bfr[j] = *(const bf16x8*)&Bc[(wn * 64 + j * 16 + r16) * BK + sw8];
    if (s + DEPTH - 1 < NSTEP) {
      int c2 = cur + DEPTH - 1; if (c2 >= DEPTH) c2 -= DEPTH;
      stage(c2, (s + DEPTH - 1) * BK);   // readers of that buf done before barrier_s
    }
#pragma unroll
    for (int i = 0; i < MI; i++)
#pragma unroll
      for (int j = 0; j < 4; j++)
        acc[i][j] = __builtin_amdgcn_mfma_f32_16x16x32_bf16(af[i], bfr[j], acc[i][j], 0, 0, 0);
    cur = cur + 1; if (cur >= DEPTH) cur = 0;
  }
  __syncthreads();    // all waves done with staging LDS before C-tile reuse

  const int m0 = (int)am0 + wm * MI * 16;   // global row base of this wave's subtile

  if constexpr (EPI == 3) {
    if (bn0 < 1536) {
      // Q or K: row-major [8192][768]. LDS C-stage in TWO 128-row passes
      // (half C-tile 34.8KB keeps smem union at the 49.2KB staging size).
      const int tens = (int)(bn0 >= 768);
      const int c0 = (int)bn0 - tens * 768;
      const float* bp = tens ? bias1 : bias0;
      u16* outb = (u16*)outp + (size_t)tens * QKV_STRIDE;
      u16* Cs = (u16*)smem;   // [128][BN+CPAD]
#pragma unroll
      for (int p = 0; p < 2; p++) {
        if ((wm >> 1) == p) {
          // waves wm in {2p, 2p+1} own rows p*128 .. p*128+127
#pragma unroll
          for (int j = 0; j < 4; j++) {
            int lc = wn * 64 + j * 16 + r16;
            float bv = bp[c0 + lc];
#pragma unroll
            for (int i = 0; i < MI; i++) {
              int lr = (wm & 1) * 64 + i * 16 + kh * 4;
#pragma unroll
              for (int r = 0; r < 4; r++)
                Cs[(lr + r) * (BN + CPAD) + lc] = f2bf(acc[i][j][r] + bv);
            }
          }
        }
        __syncthreads();
        // store 128 rows x 16 chunks = 2048 16B-chunks over NT threads
#pragma unroll
        for (int z = 0; z < 2048 / NT; z++) {
          int cidx = z * NT + tid;
          int row = cidx >> 4, ch = (cidx & 15) * 8;
          uint4 val = *(const uint4*)&Cs[row * (BN + CPAD) + ch];
          *(uint4*)(outb + (size_t)(am0 + p * 128 + row) * DMODEL + c0 + ch) = val;
        }
        __syncthreads();   // pass-0 reads done before pass-1 overwrites
      }
    } else {
      // V: block-transposed [b*12+h][t>>4][d][t&15] direct stores (no LDS)
      u16* vtb = (u16*)outp + 2 * QKV_STRIDE;
      const int kr = kh * 4;
#pragma unroll
      for (int j = 0; j < 4; j++) {
        int cl = (int)(bn0 - 1536) + wn * 64 + j * 16;   // multiple of 16, lane-uniform
        int hj = cl >> 6;
        int dlane = (cl & 63) + r16;
        float bv = bias2[cl + r16];
#pragma unroll
        for (int i = 0; i < MI; i++) {
          int row0 = m0 + i * 16;
          int b_ = row0 >> 12;
          int tb = (row0 & 4095) >> 4;
          size_t base = (((size_t)(b_ * NH + hj) * 256 + tb) << 10) + dlane * 16 + kr;
          u16x4 pk;
#pragma unroll
          for (int r = 0; r < 4; r++) pk[r] = f2bf(acc[i][j][r] + bv);
          *(u16x4*)(vtb + base) = pk;
        }
      }
    }
  } else {
    // fp32 out-proj: stage through LDS -> coalesced float4 row stores
    float* Cf = (float*)smem;   // [64][132]
#pragma unroll
    for (int j = 0; j < 4; j++) {
      int lc = wn * 64 + j * 16 + r16;
      float bv = bias0[(int)bn0 + lc];
#pragma unroll
      for (int i = 0; i < MI; i++) {
        int lr = wm * MI * 16 + i * 16 + kh * 4;
#pragma unroll
        for (int r = 0; r < 4; r++)
          Cf[(lr + r) * 132 + lc] = acc[i][j][r] + bv;
      }
    }
    __syncthreads();
    float* O = (float*)outp;
#pragma unroll
    for (int z = 0; z < 8; z++) {
      int idx = z * 256 + tid;
      int row = idx >> 5, c4 = (idx & 31) * 4;
      float4 v = *(const float4*)&Cf[row * 132 + c4];
      *(float4*)(O + (size_t)(am0 + row) * DMODEL + bn0 + c4) = v;
    }
  }
}

// ---------------- MFMA banded local attention ----------------
// r3-EXACT, single launch (measured 17.1us, r10 probe). 64 queries/block
// (4 waves x 16 queries). Per wave: 6 MFMA scores, masked softmax (intra-quad
// shfl), P -> LDS, 8 MFMA PV with V B-frags direct from transposed global,
// O staged through wave-private Ps for coalesced 128B-row stores.
#define PSS 72   // Ps row stride (u16): 144B, 16B-aligned, 2-way banks (free)

__global__ __launch_bounds__(256)
void attn_mfma(const u16* __restrict__ qkv, const u16* __restrict__ vt,
               u16* __restrict__ attn) {
  __shared__ __align__(16) u16 Ps[4][16 * PSS];   // 9216 B
  const int tid = threadIdx.x, lane = tid & 63, wave = tid >> 6;
  const int r16 = lane & 15, quad = lane >> 4;
  const int q0 = blockIdx.x * 64;
  const int h = blockIdx.y, b = blockIdx.z;
  const long rowbase = (long)b * T_LEN;
  const int hc = h * HD;
  const u16* Qg = qkv;
  const u16* Kg = qkv + QKV_STRIDE;
  const u16* Vh = vt + ((size_t)(b * NH + h)) * (256 * 1024);

  const int qbase = q0 + wave * 16;   // first query of this wave
  const int kb = qbase - 16;          // first key (mult of 16, may be <0)

  // Q A-frags: rows qbase+r16, dims quad*8 (+0 / +32)
  const u16* qrow = Qg + (rowbase + qbase + r16) * DMODEL + hc + quad * 8;
  bf16x8 qa0 = *(const bf16x8*)qrow;
  bf16x8 qa1 = *(const bf16x8*)(qrow + 32);

  // scores: 3 key tiles x (K=64 -> 2 mfma)
  f32x4 s[3];
#pragma unroll
  for (int t = 0; t < 3; t++) {
    const u16* krow = Kg + (rowbase + kb + t * 16 + r16) * DMODEL + hc + quad * 8;
    bf16x8 kf0 = *(const bf16x8*)krow;
    bf16x8 kf1 = *(const bf16x8*)(krow + 32);
    f32x4 a = {};
    __builtin_amdgcn_s_setprio(1);
    a = __builtin_amdgcn_mfma_f32_16x16x32_bf16(qa0, kf0, a, 0, 0, 0);
    a = __builtin_amdgcn_mfma_f32_16x16x32_bf16(qa1, kf1, a, 0, 0, 0);
    __builtin_amdgcn_s_setprio(0);
    s[t] = a;
  }

  // masked softmax per C-row (query = qbase + quad*4 + r), cols across quad lanes
  float pr[3][4];
#pragma unroll
  for (int r = 0; r < 4; r++) {
    const int qg = qbase + quad * 4 + r;
    float sc[3];
#pragma unroll
    for (int t = 0; t < 3; t++) {
      int key = kb + t * 16 + r16;
      bool ok = (key >= qg - 16) && (key <= qg + 16) && (key >= 0) && (key < T_LEN);
      sc[t] = ok ? s[t][r] * 0.125f : -INFINITY;
    }
    float mx = fmaxf(sc[0], fmaxf(sc[1], sc[2]));
    mx = fmaxf(mx, __shfl_xor(mx, 1));
    mx = fmaxf(mx, __shfl_xor(mx, 2));
    mx = fmaxf(mx, __shfl_xor(mx, 4));
    mx = fmaxf(mx, __shfl_xor(mx, 8));
    float e0 = __expf(sc[0] - mx), e1 = __expf(sc[1] - mx), e2 = __expf(sc[2] - mx);
    float l = e0 + e1 + e2;
    l += __shfl_xor(l, 1);
    l += __shfl_xor(l, 2);
    l += __shfl_xor(l, 4);
    l += __shfl_xor(l, 8);
    float inv = 1.0f / l;
    pr[0][r] = e0 * inv; pr[1][r] = e1 * inv; pr[2][r] = e2 * inv;
  }

  // P: C-layout -> LDS (rows=query, cols=key rel kb), zero pad cols 48..63
  u16* psw = &Ps[wave][0];
#pragma unroll
  for (int t = 0; t < 3; t++)
#pragma unroll
    for (int r = 0; r < 4; r++)
      psw[(quad * 4 + r) * PSS + t * 16 + r16] = f2bf(pr[t][r]);
#pragma unroll
  for (int r = 0; r < 4; r++)
    psw[(quad * 4 + r) * PSS + 48 + r16] = 0;

  // P A-frags (keys 0..31, 32..47+pad)
  bf16x8 pa0 = *(const bf16x8*)&psw[r16 * PSS + quad * 8];
  bf16x8 pa1 = *(const bf16x8*)&psw[r16 * PSS + 32 + quad * 8];

  // PV: 4 d-col tiles x 2 k-frags; V B-frags direct from transposed global
  const int kq1 = kb + quad * 8;
  const int kq2 = kb + 32 + quad * 8;
  const int o1 = (kq1 >> 4) * 1024 + (kq1 & 15);
  const int o2 = (kq2 >> 4) * 1024 + (kq2 & 15);
  f32x4 o[4];
#pragma unroll
  for (int c = 0; c < 4; c++) {
    const u16* vb = Vh + (16 * c + r16) * 16;
    bf16x8 v1 = *(const bf16x8*)(vb + o1);
    bf16x8 v2 = *(const bf16x8*)(vb + o2);
    f32x4 a = {};
    __builtin_amdgcn_s_setprio(1);
    a = __builtin_amdgcn_mfma_f32_16x16x32_bf16(pa0, v1, a, 0, 0, 0);
    a = __builtin_amdgcn_mfma_f32_16x16x32_bf16(pa1, v2, a, 0, 0, 0);
    __builtin_amdgcn_s_setprio(0);
    o[c] = a;
  }

  // O: stage through Ps (wave-private, P-frags already consumed), then
  // coalesced row stores: lane l handles rows l>>3 and 8+(l>>3), 16B each.
#pragma unroll
  for (int c = 0; c < 4; c++)
#pragma unroll
    for (int r = 0; r < 4; r++)
      psw[(quad * 4 + r) * PSS + 16 * c + r16] = f2bf(o[c][r]);
  {
    int rr = lane >> 3, cc = (lane & 7) * 8;
    u16x8 v0 = *(const u16x8*)&psw[rr * PSS + cc];
    u16x8 v1 = *(const u16x8*)&psw[(8 + rr) * PSS + cc];
    u16* ob = attn + (rowbase + qbase) * DMODEL + hc;
    *(u16x8*)(ob + (size_t)rr * DMODEL + cc) = v0;
    *(u16x8*)(ob + (size_t)(8 + rr) * DMODEL + cc) = v1;
  }
}

// ---------------- launch ----------------
extern "C" void kernel_launch(void* const* d_in, const int* in_sizes, int n_in,
                              void* d_out, int out_size, void* d_ws, size_t ws_size,
                              hipStream_t stream) {
  const float* x  = (const float*)d_in[0];
  const float* Wq = (const float*)d_in[1];
  const float* bq = (const float*)d_in[2];
  const float* Wk = (const float*)d_in[3];
  const float* bk = (const float*)d_in[4];
  const float* Wv = (const float*)d_in[5];
  const float* bv = (const float*)d_in[6];
  const float* Wo = (const float*)d_in[7];
  const float* bo = (const float*)d_in[8];
  float* out = (float*)d_out;
  char* ws = (char*)d_ws;

  u16* xb   = (u16*)(ws);                 // 8192*768 bf16
  u16* wqkv = (u16*)(ws + 12582912);      // 2304*768 bf16 (Wq,Wk,Wv rows)
  u16* wo_b = (u16*)(ws + 16121856);      // 768*768 bf16
  u16* qkv  = (u16*)(ws + 17301504);      // 3*6291456 bf16 (Q,K row-major; V transposed)
  u16* attnb = (u16*)(ws + 55050240);     // 8192*768 bf16

  cvt_all<<<8448, 256, 0, stream>>>(x, Wq, Wk, Wv, Wo, xb, wqkv, wo_b);

  // merged QKV projection: 256x128 tiles, 512 threads/8 waves, DEPTH=2
  // staging (49.2KB LDS -> 3 blocks/CU = 24 waves/CU; 576 blocks <= 768
  // slots = single-round grid). r14 (DEPTH=3, 2 blk/CU + tail) = 43.1us.
  gemm_bt<3, 4, 32, 8><<<576, 512, 0, stream>>>(xb, wqkv, bq, bk, bv, (void*)qkv);
  // attention: single launch (17.1us measured)
  attn_mfma<<<dim3(64, 12, 2), 256, 0, stream>>>(qkv, qkv + 2 * QKV_STRIDE, attnb);
  // out projection: MI=2, 128 x 6 = 768 blocks (21.0us measured)
  gemm_bt<1, 2, 128, 4><<<768, 256, 0, stream>>>(attnb, wo_b, bo, bo, bo, (void*)out);
}

// Round 16
// 161.358 us; speedup vs baseline: 1.0546x; 1.0546x over previous
//
#include <hip/hip_runtime.h>
#include <math.h>
#include <cstdint>
#include <cstddef>

typedef unsigned short u16;
typedef short bf16x8 __attribute__((ext_vector_type(8)));
typedef float f32x4 __attribute__((ext_vector_type(4)));
typedef u16 u16x8 __attribute__((ext_vector_type(8)));
typedef u16 u16x4 __attribute__((ext_vector_type(4)));

#define T_LEN 4096
#define NH 12
#define HD 64
#define DMODEL 768
#define GK 768                    // K dim for both GEMMs
#define QKV_STRIDE 6291456ul      // elems per q/k/v tensor = 8192*768

__device__ __forceinline__ u16 f2bf(float x) {
  union { float f; unsigned u; } v; v.f = x;
  unsigned r = v.u + 0x7fffu + ((v.u >> 16) & 1u);
  return (u16)(r >> 16);
}

__device__ __forceinline__ void async16(const u16* g, u16* l) {
  __builtin_amdgcn_global_load_lds(
      (const __attribute__((address_space(1))) unsigned int*)g,
      (__attribute__((address_space(3))) unsigned int*)l, 16, 0, 0);
}

// ---------------- fused fp32 -> bf16 conversion (x + 4 weights, one launch) ----------------
__global__ void cvt_all(const float* __restrict__ x,
                        const float* __restrict__ Wq, const float* __restrict__ Wk,
                        const float* __restrict__ Wv, const float* __restrict__ Wo,
                        u16* __restrict__ xb, u16* __restrict__ wqkv, u16* __restrict__ wo_b) {
  int bx = blockIdx.x;
  const float* s; u16* d; int base;
  if (bx < 6144)      { s = x;  d = xb;             base = bx; }
  else if (bx < 6720) { s = Wq; d = wqkv;           base = bx - 6144; }
  else if (bx < 7296) { s = Wk; d = wqkv + 589824;  base = bx - 6720; }
  else if (bx < 7872) { s = Wv; d = wqkv + 1179648; base = bx - 7296; }
  else                { s = Wo; d = wo_b;           base = bx - 7872; }
  int i = (base * 256 + (int)threadIdx.x) * 4;
  float4 v = *(const float4*)(s + i);
  u16x4 o;
  o[0] = f2bf(v.x); o[1] = f2bf(v.y); o[2] = f2bf(v.z); o[3] = f2bf(v.w);
  *(u16x4*)(d + i) = o;
}

// ---------------- GEMM: C = A[M,K] * B[N,K]^T + bias ----------------
// Triple-buffered K-loop with COUNTED vmcnt (T3+T4), skeleton verified
// r3..r14: per step {vmcnt(LPB); s_barrier; ds_read(buf s); stage(buf s+2);
// MFMA}; stage targets buf[(s-1)%3]; never vmcnt(0) in the main loop.
// MEASURED LEDGER: QKV 8w/256x128/3deep = 43.1 (r14 BEST: MfmaUtil 24.5,
// VALUBusy 16.5, Occ 27); QKV 4w/128^2/3deep = 50.2; DEPTH=2 = 48.1 (r15:
// drain exposes latency -- flight window is only the MFMA phase -- AND
// single-round 576-grid caps residency at 2.25 blk/CU, so the freed LDS
// slots were never filled. Counted-vmcnt DEPTH=3 is load-bearing.);
// attn = 17.1 (r10 probe); outproj MI=2@768 = 21.0 (r11 probe); cvt ~10;
// fixed residue ~70us (harness ws fill + graph; not source-addressable).
// r16: outproj -> MI=4/NW=4, 128x128, 384 blocks (16 MFMA/step at the same
// per-step overhead as MI=2's 8; half the block-steps). fp32 epilogue in
// TWO 64-row halves (r4-verified) keeps smem at the 49.2KB staging size.
#define BN 128
#define BK 32
#define CPAD 8   // C-tile row pad (u16) to spread LDS banks on readback

template <int EPI, int MI, int NX, int NW>
__global__ __launch_bounds__(NW * 64)
void gemm_bt(const u16* __restrict__ A, const u16* __restrict__ B,
             const float* __restrict__ bias0, const float* __restrict__ bias1,
             const float* __restrict__ bias2, void* __restrict__ outp) {
  constexpr int NT   = NW * 64;
  constexpr int BMt  = (NW == 8) ? 256 : MI * 32;
  constexpr int NSTEP = GK / BK;  // 24
  constexpr int PER = NX / 8;     // x-tiles per XCD group
  constexpr int STG = 3 * (BMt + BN) * BK * 2;                     // 3-deep staging bytes
  constexpr int CSZ = (EPI == 3) ? BMt * (BN + CPAD) * 2           // bf16 C-tile
                                 : 64 * 132 * 4;                   // f32 C-tile (64 rows)
  constexpr int SMEM = STG > CSZ ? STG : CSZ;
  __shared__ __align__(16) char smem[SMEM];
  u16* AsB = (u16*)smem;                    // [3][BMt*BK]
  u16* BsB = (u16*)smem + 3 * BMt * BK;     // [3][BN*BK]

  const int bid  = blockIdx.x;
  const int xcd  = bid & 7;
  const int slot = bid >> 3;
  const int bx   = xcd * PER + (slot % PER);
  const int by   = slot / PER;

  const int tid  = threadIdx.x;
  const int lane = tid & 63;
  const int wave = tid >> 6;
  const int wm = (NW == 8) ? (wave >> 1) : (wave & 1);
  const int wn = (NW == 8) ? (wave & 1)  : (wave >> 1);
  const long am0 = (long)bx * BMt;
  const long bn0 = (long)by * BN;
  const int r16 = lane & 15;
  const int kh  = lane >> 4;
  const int sw8 = (kh ^ ((r16 >> 1) & 3)) * 8;   // swizzled chunk offset for frag reads

  f32x4 acc[MI][4] = {};

  // staging: lane l -> row l>>2 (of a 16-row slab), global chunk
  // (l&3)^((l>>3)&3); LDS dest lane-linear (slab-local swizzle identical
  // for any wave count).
  const int srow   = lane >> 2;
  const int schunk = ((lane & 3) ^ ((lane >> 3) & 3)) * 8;
  const u16* Ag = A + (am0 + wave * 16 + srow) * GK + schunk;
  const u16* Bg = B + (bn0 + wave * 16 + srow) * GK + schunk;

  auto stage = [&](int buf, int kt) {
    u16* Ab = AsB + buf * (BMt * BK);
    u16* Bb = BsB + buf * (BN * BK);
    if constexpr (NW == 8) {
      // A: 16 slabs of 16 rows, 2 per wave (stride 128 rows); B: 8 slabs, 1/wave
#pragma unroll
      for (int s2 = 0; s2 < 2; s2++)
        async16(Ag + (size_t)(s2 * 128) * GK + kt, &Ab[(s2 * 128 + wave * 16) * BK]);
      async16(Bg + kt, &Bb[(wave * 16) * BK]);
    } else {
#pragma unroll
      for (int s2 = 0; s2 < MI / 2; s2++)
        async16(Ag + (size_t)(s2 * 64) * GK + kt, &Ab[(s2 * 64 + wave * 16) * BK]);
      async16(Bg + kt, &Bb[(wave * 16) * BK]);
      async16(Bg + (size_t)64 * GK + kt, &Bb[(64 + wave * 16) * BK]);
    }
  };

  stage(0, 0);        // batch for step 0
  stage(1, BK);       // batch for step 1
  int cur = 0;
  for (int s = 0; s < NSTEP; ++s) {
    // wait: batch s retired for this wave (only newest batch s+1 may fly)
    if (s + 1 < NSTEP) {
      if constexpr (NW == 8)      asm volatile("s_waitcnt vmcnt(3)" ::: "memory");
      else if constexpr (MI == 4) asm volatile("s_waitcnt vmcnt(4)" ::: "memory");
      else                        asm volatile("s_waitcnt vmcnt(3)" ::: "memory");
    } else {
      asm volatile("s_waitcnt vmcnt(0)" ::: "memory");
    }
    __builtin_amdgcn_s_barrier();    // all waves' batch-s loads landed
    asm volatile("" ::: "memory");
    const u16* Ac = AsB + cur * (BMt * BK);
    const u16* Bc = BsB + cur * (BN * BK);
    bf16x8 af[MI], bfr[4];
#pragma unroll
    for (int i = 0; i < MI; i++)
      af[i] = *(const bf16x8*)&Ac[(wm * MI * 16 + i * 16 + r16) * BK + sw8];
#pragma unroll
    for (int j = 0; j < 4; j++)
      bfr[j] = *(const bf16x8*)&Bc[(wn * 64 + j * 16 + r16) * BK + sw8];
    if (s + 2 < NSTEP) {
      int c2 = cur + 2; if (c2 >= 3) c2 -= 3;
      stage(c2, (s + 2) * BK);       // writes buf[(s-1)%3]: safe, after barrier_s
    }
#pragma unroll
    for (int i = 0; i < MI; i++)
#pragma unroll
      for (int j = 0; j < 4; j++)
        acc[i][j] = __builtin_amdgcn_mfma_f32_16x16x32_bf16(af[i], bfr[j], acc[i][j], 0, 0, 0);
    cur = (cur == 2) ? 0 : cur + 1;
  }
  __syncthreads();    // all waves done with staging LDS before C-tile reuse

  const int m0 = (int)am0 + wm * MI * 16;   // global row base of this wave's subtile

  if constexpr (EPI == 3) {
    if (bn0 < 1536) {
      // Q or K: row-major [8192][768], tensor selected by bn0. LDS C-stage.
      const int tens = (int)(bn0 >= 768);
      const int c0 = (int)bn0 - tens * 768;
      const float* bp = tens ? bias1 : bias0;
      u16* outb = (u16*)outp + (size_t)tens * QKV_STRIDE;
      u16* Cs = (u16*)smem;
      // 1) acc -> Cs (bf16) with bias
#pragma unroll
      for (int j = 0; j < 4; j++) {
        int lc = wn * 64 + j * 16 + r16;
        float bv = bp[c0 + lc];
#pragma unroll
        for (int i = 0; i < MI; i++) {
          int lr = wm * MI * 16 + i * 16 + kh * 4;
#pragma unroll
          for (int r = 0; r < 4; r++)
            Cs[(lr + r) * (BN + CPAD) + lc] = f2bf(acc[i][j][r] + bv);
        }
      }
      __syncthreads();
      // 2) coalesced store: BMt*16 16B-chunks (16/row), 256B contiguous per 16 lanes
#pragma unroll
      for (int z = 0; z < BMt * 16 / NT; z++) {
        int cidx = z * NT + tid;
        int row = cidx >> 4, ch = (cidx & 15) * 8;
        uint4 val = *(const uint4*)&Cs[row * (BN + CPAD) + ch];
        *(uint4*)(outb + (size_t)(am0 + row) * DMODEL + c0 + ch) = val;
      }
    } else {
      // V: block-transposed [b*12+h][t>>4][d][t&15]
      u16* vtb = (u16*)outp + 2 * QKV_STRIDE;
      const int kr = kh * 4;
#pragma unroll
      for (int j = 0; j < 4; j++) {
        int cl = (int)(bn0 - 1536) + wn * 64 + j * 16;   // multiple of 16, lane-uniform
        int hj = cl >> 6;
        int dlane = (cl & 63) + r16;
        float bv = bias2[cl + r16];
#pragma unroll
        for (int i = 0; i < MI; i++) {
          int row0 = m0 + i * 16;
          int b_ = row0 >> 12;
          int tb = (row0 & 4095) >> 4;
          size_t base = (((size_t)(b_ * NH + hj) * 256 + tb) << 10) + dlane * 16 + kr;
          u16x4 pk;
#pragma unroll
          for (int r = 0; r < 4; r++) pk[r] = f2bf(acc[i][j][r] + bv);
          *(u16x4*)(vtb + base) = pk;
        }
      }
    }
  } else {
    float* O = (float*)outp;
    float* Cf = (float*)smem;   // [64][132]
    if constexpr (MI == 2) {
      // single-pass 64x132 (r11-measured config)
#pragma unroll
      for (int j = 0; j < 4; j++) {
        int lc = wn * 64 + j * 16 + r16;
        float bv = bias0[(int)bn0 + lc];
#pragma unroll
        for (int i = 0; i < MI; i++) {
          int lr = wm * MI * 16 + i * 16 + kh * 4;
#pragma unroll
          for (int r = 0; r < 4; r++)
            Cf[(lr + r) * 132 + lc] = acc[i][j][r] + bv;
        }
      }
      __syncthreads();
#pragma unroll
      for (int z = 0; z < 8; z++) {
        int idx = z * 256 + tid;
        int row = idx >> 5, c4 = (idx & 31) * 4;
        float4 v = *(const float4*)&Cf[row * 132 + c4];
        *(float4*)(O + (size_t)(am0 + row) * DMODEL + bn0 + c4) = v;
      }
    } else {
      // MI=4: two 64-row halves (r4-verified); half h written by waves wm==h
#pragma unroll
      for (int half = 0; half < 2; half++) {
        if (wm == half) {
#pragma unroll
          for (int j = 0; j < 4; j++) {
            int lc = wn * 64 + j * 16 + r16;
            float bv = bias0[(int)bn0 + lc];
#pragma unroll
            for (int i = 0; i < MI; i++) {
              int lr = i * 16 + kh * 4;
#pragma unroll
              for (int r = 0; r < 4; r++)
                Cf[(lr + r) * 132 + lc] = acc[i][j][r] + bv;
            }
          }
        }
        __syncthreads();
        // 64 rows x 128 cols of f32 = MI*2*256 float4 chunks
#pragma unroll
        for (int z = 0; z < MI * 2; z++) {
          int idx = z * 256 + tid;
          int row = idx >> 5, c4 = (idx & 31) * 4;
          float4 v = *(const float4*)&Cf[row * 132 + c4];
          *(float4*)(O + (size_t)(am0 + half * 64 + row) * DMODEL + bn0 + c4) = v;
        }
        __syncthreads();   // half-0 reads done before half-1 overwrites
      }
    }
  }
}

// ---------------- MFMA banded local attention ----------------
// r3-EXACT, single launch (measured 17.1us, r10 probe). 64 queries/block
// (4 waves x 16 queries). Per wave: 6 MFMA scores, masked softmax (intra-quad
// shfl), P -> LDS, 8 MFMA PV with V B-frags direct from transposed global,
// O staged through wave-private Ps for coalesced 128B-row stores.
#define PSS 72   // Ps row stride (u16): 144B, 16B-aligned, 2-way banks (free)

__global__ __launch_bounds__(256)
void attn_mfma(const u16* __restrict__ qkv, const u16* __restrict__ vt,
               u16* __restrict__ attn) {
  __shared__ __align__(16) u16 Ps[4][16 * PSS];   // 9216 B
  const int tid = threadIdx.x, lane = tid & 63, wave = tid >> 6;
  const int r16 = lane & 15, quad = lane >> 4;
  const int q0 = blockIdx.x * 64;
  const int h = blockIdx.y, b = blockIdx.z;
  const long rowbase = (long)b * T_LEN;
  const int hc = h * HD;
  const u16* Qg = qkv;
  const u16* Kg = qkv + QKV_STRIDE;
  const u16* Vh = vt + ((size_t)(b * NH + h)) * (256 * 1024);

  const int qbase = q0 + wave * 16;   // first query of this wave
  const int kb = qbase - 16;          // first key (mult of 16, may be <0)

  // Q A-frags: rows qbase+r16, dims quad*8 (+0 / +32)
  const u16* qrow = Qg + (rowbase + qbase + r16) * DMODEL + hc + quad * 8;
  bf16x8 qa0 = *(const bf16x8*)qrow;
  bf16x8 qa1 = *(const bf16x8*)(qrow + 32);

  // scores: 3 key tiles x (K=64 -> 2 mfma)
  f32x4 s[3];
#pragma unroll
  for (int t = 0; t < 3; t++) {
    const u16* krow = Kg + (rowbase + kb + t * 16 + r16) * DMODEL + hc + quad * 8;
    bf16x8 kf0 = *(const bf16x8*)krow;
    bf16x8 kf1 = *(const bf16x8*)(krow + 32);
    f32x4 a = {};
    __builtin_amdgcn_s_setprio(1);
    a = __builtin_amdgcn_mfma_f32_16x16x32_bf16(qa0, kf0, a, 0, 0, 0);
    a = __builtin_amdgcn_mfma_f32_16x16x32_bf16(qa1, kf1, a, 0, 0, 0);
    __builtin_amdgcn_s_setprio(0);
    s[t] = a;
  }

  // masked softmax per C-row (query = qbase + quad*4 + r), cols across quad lanes
  float pr[3][4];
#pragma unroll
  for (int r = 0; r < 4; r++) {
    const int qg = qbase + quad * 4 + r;
    float sc[3];
#pragma unroll
    for (int t = 0; t < 3; t++) {
      int key = kb + t * 16 + r16;
      bool ok = (key >= qg - 16) && (key <= qg + 16) && (key >= 0) && (key < T_LEN);
      sc[t] = ok ? s[t][r] * 0.125f : -INFINITY;
    }
    float mx = fmaxf(sc[0], fmaxf(sc[1], sc[2]));
    mx = fmaxf(mx, __shfl_xor(mx, 1));
    mx = fmaxf(mx, __shfl_xor(mx, 2));
    mx = fmaxf(mx, __shfl_xor(mx, 4));
    mx = fmaxf(mx, __shfl_xor(mx, 8));
    float e0 = __expf(sc[0] - mx), e1 = __expf(sc[1] - mx), e2 = __expf(sc[2] - mx);
    float l = e0 + e1 + e2;
    l += __shfl_xor(l, 1);
    l += __shfl_xor(l, 2);
    l += __shfl_xor(l, 4);
    l += __shfl_xor(l, 8);
    float inv = 1.0f / l;
    pr[0][r] = e0 * inv; pr[1][r] = e1 * inv; pr[2][r] = e2 * inv;
  }

  // P: C-layout -> LDS (rows=query, cols=key rel kb), zero pad cols 48..63
  u16* psw = &Ps[wave][0];
#pragma unroll
  for (int t = 0; t < 3; t++)
#pragma unroll
    for (int r = 0; r < 4; r++)
      psw[(quad * 4 + r) * PSS + t * 16 + r16] = f2bf(pr[t][r]);
#pragma unroll
  for (int r = 0; r < 4; r++)
    psw[(quad * 4 + r) * PSS + 48 + r16] = 0;

  // P A-frags (keys 0..31, 32..47+pad)
  bf16x8 pa0 = *(const bf16x8*)&psw[r16 * PSS + quad * 8];
  bf16x8 pa1 = *(const bf16x8*)&psw[r16 * PSS + 32 + quad * 8];

  // PV: 4 d-col tiles x 2 k-frags; V B-frags direct from transposed global
  const int kq1 = kb + quad * 8;
  const int kq2 = kb + 32 + quad * 8;
  const int o1 = (kq1 >> 4) * 1024 + (kq1 & 15);
  const int o2 = (kq2 >> 4) * 1024 + (kq2 & 15);
  f32x4 o[4];
#pragma unroll
  for (int c = 0; c < 4; c++) {
    const u16* vb = Vh + (16 * c + r16) * 16;
    bf16x8 v1 = *(const bf16x8*)(vb + o1);
    bf16x8 v2 = *(const bf16x8*)(vb + o2);
    f32x4 a = {};
    __builtin_amdgcn_s_setprio(1);
    a = __builtin_amdgcn_mfma_f32_16x16x32_bf16(pa0, v1, a, 0, 0, 0);
    a = __builtin_amdgcn_mfma_f32_16x16x32_bf16(pa1, v2, a, 0, 0, 0);
    __builtin_amdgcn_s_setprio(0);
    o[c] = a;
  }

  // O: stage through Ps (wave-private, P-frags already consumed), then
  // coalesced row stores: lane l handles rows l>>3 and 8+(l>>3), 16B each.
#pragma unroll
  for (int c = 0; c < 4; c++)
#pragma unroll
    for (int r = 0; r < 4; r++)
      psw[(quad * 4 + r) * PSS + 16 * c + r16] = f2bf(o[c][r]);
  {
    int rr = lane >> 3, cc = (lane & 7) * 8;
    u16x8 v0 = *(const u16x8*)&psw[rr * PSS + cc];
    u16x8 v1 = *(const u16x8*)&psw[(8 + rr) * PSS + cc];
    u16* ob = attn + (rowbase + qbase) * DMODEL + hc;
    *(u16x8*)(ob + (size_t)rr * DMODEL + cc) = v0;
    *(u16x8*)(ob + (size_t)(8 + rr) * DMODEL + cc) = v1;
  }
}

// ---------------- launch ----------------
extern "C" void kernel_launch(void* const* d_in, const int* in_sizes, int n_in,
                              void* d_out, int out_size, void* d_ws, size_t ws_size,
                              hipStream_t stream) {
  const float* x  = (const float*)d_in[0];
  const float* Wq = (const float*)d_in[1];
  const float* bq = (const float*)d_in[2];
  const float* Wk = (const float*)d_in[3];
  const float* bk = (const float*)d_in[4];
  const float* Wv = (const float*)d_in[5];
  const float* bv = (const float*)d_in[6];
  const float* Wo = (const float*)d_in[7];
  const float* bo = (const float*)d_in[8];
  float* out = (float*)d_out;
  char* ws = (char*)d_ws;

  u16* xb   = (u16*)(ws);                 // 8192*768 bf16
  u16* wqkv = (u16*)(ws + 12582912);      // 2304*768 bf16 (Wq,Wk,Wv rows)
  u16* wo_b = (u16*)(ws + 16121856);      // 768*768 bf16
  u16* qkv  = (u16*)(ws + 17301504);      // 3*6291456 bf16 (Q,K row-major; V transposed)
  u16* attnb = (u16*)(ws + 55050240);     // 8192*768 bf16

  cvt_all<<<8448, 256, 0, stream>>>(x, Wq, Wk, Wv, Wo, xb, wqkv, wo_b);

  // merged QKV projection: r14-EXACT (43.1us measured): 256x128 tiles,
  // 512 threads/8 waves, DEPTH=3 counted vmcnt, 32 x 18 = 576 blocks
  gemm_bt<3, 4, 32, 8><<<576, 512, 0, stream>>>(xb, wqkv, bq, bk, bv, (void*)qkv);
  // attention: single launch (17.1us measured)
  attn_mfma<<<dim3(64, 12, 2), 256, 0, stream>>>(qkv, qkv + 2 * QKV_STRIDE, attnb);
  // out projection: MI=4/NW=4, 128x128, 64 x 6 = 384 blocks (was MI=2@768 =
  // 21.0us: 8 MFMA/step at full per-step overhead; this halves block-steps)
  gemm_bt<1, 4, 64, 4><<<384, 256, 0, stream>>>(attnb, wo_b, bo, bo, bo, (void*)out);
}